// Round 7
// baseline (297.787 us; speedup 1.0000x reference)
//
#include <hip/hip_runtime.h>

#define B_ 4
#define S_ 1024
#define E_ 2048
#define H_ 32
#define D_ 64

typedef __attribute__((ext_vector_type(4))) float f32x4;
typedef __attribute__((ext_vector_type(8))) short s16x8;
typedef __attribute__((ext_vector_type(4))) unsigned short u16x4;
typedef __attribute__((ext_vector_type(8))) unsigned short u16x8;

__device__ inline unsigned short f2bf(float f) {
  unsigned int u = __float_as_uint(f);
  u += 0x7fff + ((u >> 16) & 1);   // round-to-nearest-even
  return (unsigned short)(u >> 16);
}

__device__ inline void gl_lds16(const unsigned short* g, unsigned short* l) {
  __builtin_amdgcn_global_load_lds(
      (const __attribute__((address_space(1))) unsigned int*)g,
      (__attribute__((address_space(3))) unsigned int*)l,
      16, 0, 0);
}

// ---------------- fp32 -> bf16 convert (8 elems/thread) ----------------
__global__ __launch_bounds__(256) void convertk(const float* __restrict__ in,
                                                unsigned short* __restrict__ out,
                                                int n8) {
  int i = blockIdx.x * 256 + threadIdx.x;
  if (i >= n8) return;
  const float4* p = (const float4*)in + (size_t)i * 2;
  float4 a = p[0], b = p[1];
  u16x8 o;
  o[0] = f2bf(a.x); o[1] = f2bf(a.y); o[2] = f2bf(a.z); o[3] = f2bf(a.w);
  o[4] = f2bf(b.x); o[5] = f2bf(b.y); o[6] = f2bf(b.z); o[7] = f2bf(b.w);
  *((u16x8*)out + i) = o;
}

// convert 4 weight matrices in one launch (grid.y selects)
__global__ __launch_bounds__(256) void convertw4(const float* __restrict__ Wq,
                                                 const float* __restrict__ Wk,
                                                 const float* __restrict__ Wv,
                                                 const float* __restrict__ Wo,
                                                 unsigned short* __restrict__ out,
                                                 int n8) {
  int y = blockIdx.y;
  const float* src = y == 0 ? Wq : (y == 1 ? Wk : (y == 2 ? Wv : Wo));
  int i = blockIdx.x * 256 + threadIdx.x;
  if (i >= n8) return;
  const float4* p = (const float4*)src + (size_t)i * 2;
  float4 a = p[0], b = p[1];
  u16x8 o;
  o[0] = f2bf(a.x); o[1] = f2bf(a.y); o[2] = f2bf(a.z); o[3] = f2bf(a.w);
  o[4] = f2bf(b.x); o[5] = f2bf(b.y); o[6] = f2bf(b.z); o[7] = f2bf(b.w);
  *((u16x8*)out + (size_t)y * n8 + i) = o;
}

// ---- 128x256 GEMM, BK=64, TRIPLE-buffered LDS, 1 barrier/K-tile ----------
// MODE 0: fused QKV. Logical N=6144: tn 0-7 -> Q, 8-15 -> K, 16-23 -> V(t).
// MODE 1: O-proj, fp32 out, N=2048.
// 512 thr / 8 waves (2M x 4N), wave tile 64x64.
// Triple buffer: tile t in buf[t%3]; STAGE(t+2) issued after the tile-entry
// barrier -> never overlaps readers (buf[(t+2)%3] was fully read before the
// PREVIOUS barrier). Counted vmcnt(6): t's loads landed, t+1's in flight.
// T2 both-sides XOR swizzle; T5 setprio around MFMA cluster.
template <int MODE>
__global__ __launch_bounds__(512, 2) void gemmT(
    const unsigned short* __restrict__ A,
    const unsigned short* __restrict__ W0,
    const unsigned short* __restrict__ W1,
    const unsigned short* __restrict__ W2,
    const float* __restrict__ b0, const float* __restrict__ b1,
    const float* __restrict__ b2,
    unsigned short* __restrict__ O0, unsigned short* __restrict__ O1,
    unsigned short* __restrict__ O2, float* __restrict__ OF) {
  __shared__ __align__(16) unsigned short lA[3][128 * 64];
  __shared__ __align__(16) unsigned short lB[3][256 * 64];
  int tid = threadIdx.x;
  int w = tid >> 6, lane = tid & 63;
  int row16 = lane & 15, grp = lane >> 4;
  int wm = w >> 2, wn = w & 3;            // 2x4 waves; wave tile 64x64
  int srow = tid >> 3;                     // staging row 0..63 per round
  int sx = tid & 7;                        // 16B slot in 128B row
  int sswz = (sx ^ (srow & 7)) * 8;        // pre-swizzled elem offset

  int nwg = gridDim.x;
  int bid = blockIdx.x;
  int swz = (bid & 7) * (nwg >> 3) + (bid >> 3);
  const int NT = (MODE == 0) ? 24 : 8;
  int tm = swz / NT, tn = swz % NT;
  int seg = (MODE == 0) ? (tn >> 3) : 0;
  const unsigned short* Bsrc =
      (MODE == 0) ? (seg == 0 ? W0 : (seg == 1 ? W1 : W2)) : W0;
  int rowA0 = tm * 128;
  int rowB0 = (tn - seg * 8) * 256;

  f32x4 acc[4][4] = {};

#define STG(BUF, K0)                                                        \
  { _Pragma("unroll") for (int c = 0; c < 2; c++) {                         \
      gl_lds16(A + (size_t)(rowA0 + c * 64 + srow) * 2048 + (K0) + sswz,    \
               &lA[BUF][0] + (c * 64 + w * 8) * 64); }                      \
    _Pragma("unroll") for (int c = 0; c < 4; c++) {                         \
      gl_lds16(Bsrc + (size_t)(rowB0 + c * 64 + srow) * 2048 + (K0) + sswz, \
               &lB[BUF][0] + (c * 64 + w * 8) * 64); } }

  STG(0, 0)
  STG(1, 64)

  int xr = row16 & 7;
  for (int t = 0; t < 32; t++) {
    if (t < 31) asm volatile("s_waitcnt vmcnt(6)" ::: "memory");
    else        asm volatile("s_waitcnt vmcnt(0)" ::: "memory");
    __builtin_amdgcn_sched_barrier(0);
    __builtin_amdgcn_s_barrier();
    __builtin_amdgcn_sched_barrier(0);
    int buf = t % 3;
    if (t < 30) { int nb = (t + 2) % 3; STG(nb, (t + 2) * 64) }
    const unsigned short* As = &lA[buf][0];
    const unsigned short* Bs = &lB[buf][0];
    s16x8 af[2][4], bf[2][4];
#pragma unroll
    for (int kk = 0; kk < 2; kk++) {
      int so = ((kk * 4 + grp) ^ xr) * 8;
#pragma unroll
      for (int i = 0; i < 4; i++)
        af[kk][i] = *(const s16x8*)(As + (wm * 64 + i * 16 + row16) * 64 + so);
#pragma unroll
      for (int j = 0; j < 4; j++)
        bf[kk][j] = *(const s16x8*)(Bs + (wn * 64 + j * 16 + row16) * 64 + so);
    }
    __builtin_amdgcn_s_setprio(1);
#pragma unroll
    for (int kk = 0; kk < 2; kk++)
#pragma unroll
      for (int i = 0; i < 4; i++)
#pragma unroll
        for (int j = 0; j < 4; j++)
          acc[i][j] = __builtin_amdgcn_mfma_f32_16x16x32_bf16(af[kk][i], bf[kk][j], acc[i][j], 0, 0, 0);
    __builtin_amdgcn_s_setprio(0);
  }
#undef STG

  int row0 = rowA0 + wm * 64 + grp * 4;
  int col0 = (tn - seg * 8) * 256 + wn * 64 + row16;
  if (MODE == 1) {
#pragma unroll
    for (int i = 0; i < 4; i++)
#pragma unroll
      for (int j = 0; j < 4; j++) {
        int col = col0 + j * 16;
        float bvv = b0[col];
#pragma unroll
        for (int r = 0; r < 4; r++)
          OF[(size_t)(row0 + i * 16 + r) * 2048 + col] = acc[i][j][r] + bvv;
      }
  } else if (seg == 0) {
    const float QSC = 0.18033688011112042f;  // 0.125 * log2(e)
#pragma unroll
    for (int i = 0; i < 4; i++)
#pragma unroll
      for (int j = 0; j < 4; j++) {
        int col = col0 + j * 16;
        float bvv = b0[col];
#pragma unroll
        for (int r = 0; r < 4; r++)
          O0[(size_t)(row0 + i * 16 + r) * 2048 + col] = f2bf((acc[i][j][r] + bvv) * QSC);
      }
  } else if (seg == 1) {
#pragma unroll
    for (int i = 0; i < 4; i++)
#pragma unroll
      for (int j = 0; j < 4; j++) {
        int col = col0 + j * 16;
        float bvv = b1[col];
#pragma unroll
        for (int r = 0; r < 4; r++)
          O1[(size_t)(row0 + i * 16 + r) * 2048 + col] = f2bf(acc[i][j][r] + bvv);
      }
  } else {
#pragma unroll
    for (int i = 0; i < 4; i++)
#pragma unroll
      for (int j = 0; j < 4; j++) {
        int col = col0 + j * 16;
        float bvv = b2[col];
        int hh = col >> 6, dd = col & 63;
        int rowb = row0 + i * 16;
        int bb = rowb >> 10, s0v = rowb & 1023;
        u16x4 pk;
#pragma unroll
        for (int r = 0; r < 4; r++) pk[r] = f2bf(acc[i][j][r] + bvv);
        *(u16x4*)(O2 + (((size_t)(bb * H_ + hh)) * D_ + dd) * S_ + s0v) = pk;
      }
  }
}

// ---------------- flash attention (paired-causal, balanced) ----------------
// Block = (b, h, pair p): q-groups p and 15-p share K/V LDS staging -> every
// block does 17 chunk-steps. Scores pre-scaled by log2(e) -> exp2f.
__global__ __launch_bounds__(256, 4) void attnk(const unsigned short* __restrict__ Q,
                                                const unsigned short* __restrict__ K,
                                                const unsigned short* __restrict__ Vt,
                                                unsigned short* __restrict__ ctx) {
  __shared__ unsigned short KT[2][64 * 64];
  __shared__ unsigned short VT[2][64 * 64];
  __shared__ unsigned short Pl[4][16 * 64];
  int tid = threadIdx.x;
  int w = tid >> 6, lane = tid & 63;
  int row16 = lane & 15, grp = lane >> 4;
  int bid = blockIdx.x;
  int bh = bid >> 3;
  int p = bid & 7;
  int b = bh >> 5, h = bh & 31;
  int qgA = p, qgB = 15 - p;
  int qA = qgA * 64 + w * 16 + row16;
  int qB = qgB * 64 + w * 16 + row16;
  int nkc = qgB + 1;

  const unsigned short* qpA = Q + ((size_t)(b * S_ + qA)) * E_ + h * D_ + grp * 8;
  const unsigned short* qpB = Q + ((size_t)(b * S_ + qB)) * E_ + h * D_ + grp * 8;
  s16x8 qfA0 = *(const s16x8*)(qpA);
  s16x8 qfA1 = *(const s16x8*)(qpA + 32);
  s16x8 qfB0 = *(const s16x8*)(qpB);
  s16x8 qfB1 = *(const s16x8*)(qpB + 32);

  f32x4 oaccA[4] = {}, oaccB[4] = {};
  float mA = -1e30f, lAr = 0.f, mB = -1e30f, lBr = 0.f;

  int trow = tid >> 3;
  int tslot = tid & 7;
  const unsigned short* Kg = K + ((size_t)(b * S_)) * E_ + h * D_;
  const unsigned short* Vg = Vt + (((size_t)(b * H_ + h)) * D_) * S_;
  unsigned short* P = Pl[w];

  auto tstep = [&](s16x8 q0f, s16x8 q1f, int qloc, f32x4* oa, float& mr,
                   float& lr, bool diag, const unsigned short* Kt,
                   const unsigned short* Vl) {
    f32x4 s[4];
#pragma unroll
    for (int j = 0; j < 4; j++) {
      int krow = 16 * j + row16;
      s16x8 kf0 = *(const s16x8*)(Kt + krow * 64 + ((grp ^ (krow & 7)) * 8));
      s16x8 kf1 = *(const s16x8*)(Kt + krow * 64 + (((grp + 4) ^ (krow & 7)) * 8));
      f32x4 a = {};
      a = __builtin_amdgcn_mfma_f32_16x16x32_bf16(kf0, q0f, a, 0, 0, 0);
      a = __builtin_amdgcn_mfma_f32_16x16x32_bf16(kf1, q1f, a, 0, 0, 0);
      s[j] = a;
    }
    float mx = -1e30f;
    if (diag) {
#pragma unroll
      for (int j = 0; j < 4; j++)
#pragma unroll
        for (int r = 0; r < 4; r++) {
          int key = 16 * j + grp * 4 + r;
          float sv = (key <= qloc) ? s[j][r] : -1e30f;
          s[j][r] = sv;
          mx = fmaxf(mx, sv);
        }
    } else {
#pragma unroll
      for (int j = 0; j < 4; j++)
#pragma unroll
        for (int r = 0; r < 4; r++) mx = fmaxf(mx, s[j][r]);
    }
    mx = fmaxf(mx, __shfl_xor(mx, 16));
    mx = fmaxf(mx, __shfl_xor(mx, 32));
    float mn = fmaxf(mr, mx);
    float sc = exp2f(mr - mn);
    mr = mn;
    float rs = 0.f;
#pragma unroll
    for (int j = 0; j < 4; j++)
#pragma unroll
      for (int r = 0; r < 4; r++) {
        float e = exp2f(s[j][r] - mn);
        s[j][r] = e;
        rs += e;
      }
    rs += __shfl_xor(rs, 16);
    rs += __shfl_xor(rs, 32);
    lr = lr * sc + rs;
#pragma unroll
    for (int dt = 0; dt < 4; dt++) oa[dt] *= sc;
#pragma unroll
    for (int j = 0; j < 4; j++) {
      u16x4 pk;
#pragma unroll
      for (int r = 0; r < 4; r++) pk[r] = f2bf(s[j][r]);
      int s8 = 4 * j + grp;
      *(u16x4*)(P + row16 * 64 + ((s8 * 4) ^ ((row16 & 7) << 3))) = pk;
    }
    s16x8 pb0 = *(const s16x8*)(P + row16 * 64 + ((grp * 8) ^ ((row16 & 7) << 3)));
    s16x8 pb1 = *(const s16x8*)(P + row16 * 64 + (((4 + grp) * 8) ^ ((row16 & 7) << 3)));
#pragma unroll
    for (int dt = 0; dt < 4; dt++) {
      int drow = dt * 16 + row16;
      s16x8 vf0 = *(const s16x8*)(Vl + drow * 64 + ((grp ^ (drow & 7)) * 8));
      s16x8 vf1 = *(const s16x8*)(Vl + drow * 64 + (((grp + 4) ^ (drow & 7)) * 8));
      oa[dt] = __builtin_amdgcn_mfma_f32_16x16x32_bf16(vf0, pb0, oa[dt], 0, 0, 0);
      oa[dt] = __builtin_amdgcn_mfma_f32_16x16x32_bf16(vf1, pb1, oa[dt], 0, 0, 0);
    }
  };

#pragma unroll
  for (int c = 0; c < 2; c++) {
    int krow = c * 32 + trow;
    gl_lds16(Kg + (size_t)krow * E_ + ((tslot ^ (krow & 7)) * 8),
             &KT[0][0] + c * 2048 + w * 512);
    gl_lds16(Vg + (size_t)krow * S_ + ((tslot ^ (krow & 7)) * 8),
             &VT[0][0] + c * 2048 + w * 512);
  }
  __syncthreads();

  for (int kc = 0; kc < nkc; kc++) {
    int cur = kc & 1;
    if (kc + 1 < nkc) {
      int k0n = (kc + 1) * 64;
      int nxt = cur ^ 1;
#pragma unroll
      for (int c = 0; c < 2; c++) {
        int krow = c * 32 + trow;
        gl_lds16(Kg + (size_t)(k0n + krow) * E_ + ((tslot ^ (krow & 7)) * 8),
                 &KT[nxt][0] + c * 2048 + w * 512);
        gl_lds16(Vg + (size_t)krow * S_ + k0n + ((tslot ^ (krow & 7)) * 8),
                 &VT[nxt][0] + c * 2048 + w * 512);
      }
    }
    int k0 = kc * 64;
    const unsigned short* Kt = &KT[cur][0];
    const unsigned short* Vl = &VT[cur][0];

    tstep(qfB0, qfB1, qB - k0, oaccB, mB, lBr, kc == qgB, Kt, Vl);
    if (kc <= qgA)
      tstep(qfA0, qfA1, qA - k0, oaccA, mA, lAr, kc == qgA, Kt, Vl);
    __syncthreads();
  }

  float invB = 1.0f / lBr, invA = 1.0f / lAr;
  unsigned short* cpB = ctx + ((size_t)(b * S_ + qB)) * E_ + h * D_;
  unsigned short* cpA = ctx + ((size_t)(b * S_ + qA)) * E_ + h * D_;
#pragma unroll
  for (int dt = 0; dt < 4; dt++) {
    u16x4 oB, oA;
#pragma unroll
    for (int r = 0; r < 4; r++) {
      oB[r] = f2bf(oaccB[dt][r] * invB);
      oA[r] = f2bf(oaccA[dt][r] * invA);
    }
    *(u16x4*)(cpB + dt * 16 + grp * 4) = oB;
    *(u16x4*)(cpA + dt * 16 + grp * 4) = oA;
  }
}

extern "C" void kernel_launch(void* const* d_in, const int* in_sizes, int n_in,
                              void* d_out, int out_size, void* d_ws, size_t ws_size,
                              hipStream_t stream) {
  const float* X    = (const float*)d_in[0];
  const float* Wq   = (const float*)d_in[2];
  const float* bq   = (const float*)d_in[3];
  const float* Wk   = (const float*)d_in[4];
  const float* bk   = (const float*)d_in[5];
  const float* Wv   = (const float*)d_in[6];
  const float* bv   = (const float*)d_in[7];
  const float* Wo   = (const float*)d_in[8];
  const float* bo   = (const float*)d_in[9];
  float* out = (float*)d_out;

  // ---- memory map (peak ws use: 64MB; Q/K live in d_out until gemm_o) ----
  // ws:    [0,16)MB  Xbf (X bf16; reused as ctx after attn)
  //        [16,24)   Wq bf16   [24,32) Wk   [32,40) Wv   [56,64) Wo
  //        [40,56)   Vt (V transposed per-head, bf16)
  // d_out: [0,16)MB  Qbf   [16,32) Kbf   -- overwritten by gemmT<1> at end
  char* ws = (char*)d_ws;
  unsigned short* Xbf  = (unsigned short*)ws;
  unsigned short* Wqbf = (unsigned short*)(ws + (16u << 20));
  unsigned short* Wkbf = Wqbf + (size_t)E_ * E_;
  unsigned short* Wvbf = Wkbf + (size_t)E_ * E_;
  unsigned short* Vt   = (unsigned short*)(ws + (40u << 20));
  unsigned short* Wobf = (unsigned short*)(ws + (56u << 20));
  unsigned short* Qbf  = (unsigned short*)d_out;
  unsigned short* Kbf  = Qbf + (size_t)(B_ * S_) * E_;

  const int M = B_ * S_;   // 4096
  const int nX8 = (B_ * S_ * E_) / 8;
  const int nW8 = (E_ * E_) / 8;

  convertk<<<nX8 / 256, 256, 0, stream>>>(X, Xbf, nX8);
  convertw4<<<dim3(nW8 / 256, 4), 256, 0, stream>>>(Wq, Wk, Wv, Wo, Wqbf, nW8);
  // note: convertw4 writes Wq,Wk,Wv contiguously then Wo at y=3 -> place Wo
  // pointer accordingly (y*n8 layout): y=3 slot == Wqbf + 3*E*E == ws+40MB,
  // which collides with Vt! Redirect: convert Wo separately into Wobf.
  // (kept as its own tiny launch to preserve the Vt slot)
  convertk<<<nW8 / 256, 256, 0, stream>>>(Wo, Wobf, nW8);

  gemmT<0><<<(M / 128) * 24, 512, 0, stream>>>(
      Xbf, Wqbf, Wkbf, Wvbf, bq, bk, bv, Qbf, Kbf, Vt, nullptr);

  attnk<<<B_ * H_ * 8, 256, 0, stream>>>(Qbf, Kbf, Vt, Xbf);

  gemmT<1><<<(M / 128) * 8, 512, 0, stream>>>(
      Xbf, Wobf, nullptr, nullptr, bo, nullptr, nullptr,
      nullptr, nullptr, nullptr, out);
}

// Round 8
// 277.656 us; speedup vs baseline: 1.0725x; 1.0725x over previous
//
#include <hip/hip_runtime.h>

#define B_ 4
#define S_ 1024
#define E_ 2048
#define H_ 32
#define D_ 64

typedef __attribute__((ext_vector_type(4))) float f32x4;
typedef __attribute__((ext_vector_type(8))) short s16x8;
typedef __attribute__((ext_vector_type(4))) unsigned short u16x4;
typedef __attribute__((ext_vector_type(8))) unsigned short u16x8;

__device__ inline unsigned short f2bf(float f) {
  unsigned int u = __float_as_uint(f);
  u += 0x7fff + ((u >> 16) & 1);   // round-to-nearest-even
  return (unsigned short)(u >> 16);
}

__device__ inline void gl_lds16(const unsigned short* g, unsigned short* l) {
  __builtin_amdgcn_global_load_lds(
      (const __attribute__((address_space(1))) unsigned int*)g,
      (__attribute__((address_space(3))) unsigned int*)l,
      16, 0, 0);
}

// ---------------- fp32 -> bf16 convert (8 elems/thread) ----------------
__global__ __launch_bounds__(256) void convertk(const float* __restrict__ in,
                                                unsigned short* __restrict__ out,
                                                int n8) {
  int i = blockIdx.x * 256 + threadIdx.x;
  if (i >= n8) return;
  const float4* p = (const float4*)in + (size_t)i * 2;
  float4 a = p[0], b = p[1];
  u16x8 o;
  o[0] = f2bf(a.x); o[1] = f2bf(a.y); o[2] = f2bf(a.z); o[3] = f2bf(a.w);
  o[4] = f2bf(b.x); o[5] = f2bf(b.y); o[6] = f2bf(b.z); o[7] = f2bf(b.w);
  *((u16x8*)out + i) = o;
}

__global__ __launch_bounds__(256) void convertw3(const float* __restrict__ Wq,
                                                 const float* __restrict__ Wk,
                                                 const float* __restrict__ Wv,
                                                 unsigned short* __restrict__ out,
                                                 int n8) {
  int y = blockIdx.y;
  const float* src = y == 0 ? Wq : (y == 1 ? Wk : Wv);
  int i = blockIdx.x * 256 + threadIdx.x;
  if (i >= n8) return;
  const float4* p = (const float4*)src + (size_t)i * 2;
  float4 a = p[0], b = p[1];
  u16x8 o;
  o[0] = f2bf(a.x); o[1] = f2bf(a.y); o[2] = f2bf(a.z); o[3] = f2bf(a.w);
  o[4] = f2bf(b.x); o[5] = f2bf(b.y); o[6] = f2bf(b.z); o[7] = f2bf(b.w);
  *((u16x8*)out + (size_t)y * n8 + i) = o;
}

// ---- fused QKV GEMM: 256x256 tile, BK=64, 8-PHASE schedule (m201 port) ----
// 512 thr / 8 waves (2M x 4N), wave tile 128x64. LDS 128KB: 2 buf x 2 half
// (128x64) x {A,B}. Per K-tile 4 phases = 4 C-quadrants, each:
//   {ds_read subtile || stage 1 half-tile} -> barrier -> lgkm(0) -> 16 MFMA
//   -> barrier.   Stage map: p0:A0(t+1) p1:A1(t+1) p2:B0(t+2) p3:B1(t+2).
// vmcnt(4) once per K-tile at p3 (2 half-tiles always in flight).
__global__ __launch_bounds__(512, 2) void gemm_qkv8(
    const unsigned short* __restrict__ A,
    const unsigned short* __restrict__ Wqb,
    const unsigned short* __restrict__ Wkb,
    const unsigned short* __restrict__ Wvb,
    const float* __restrict__ bq, const float* __restrict__ bk,
    const float* __restrict__ bv,
    unsigned short* __restrict__ Qo, unsigned short* __restrict__ Ko,
    unsigned short* __restrict__ Vo) {
  __shared__ __align__(16) unsigned short lA[2][2 * 128 * 64];
  __shared__ __align__(16) unsigned short lB[2][2 * 128 * 64];
  int tid = threadIdx.x;
  int w = tid >> 6, lane = tid & 63;
  int row16 = lane & 15, grp = lane >> 4;
  int wm = w >> 2, wn = w & 3;       // 2x4 wave grid
  int srow8 = tid >> 3;              // staging row 0..63 per load
  int sx = tid & 7;

  int nwg = gridDim.x;               // 384
  int bid = blockIdx.x;
  int swz = (bid & 7) * (nwg >> 3) + (bid >> 3);
  int tm = swz / 24, tn = swz % 24;
  int seg = tn >> 3;                 // 0:Q 1:K 2:V
  const unsigned short* Bsrc = seg == 0 ? Wqb : (seg == 1 ? Wkb : Wvb);
  int rowA0 = tm * 256;
  int rowB0 = (tn - seg * 8) * 256;

  f32x4 acc[8][4] = {};

  // stage one 128-row half-tile (2 x gl_lds per thread)
#define STGH(G, RB, K0, L)                                                  \
  { _Pragma("unroll") for (int l = 0; l < 2; l++) {                         \
      int r = l * 64 + srow8;                                               \
      gl_lds16((G) + (size_t)((RB) + r) * 2048 + (K0) + ((sx ^ (r & 7)) * 8), \
               (L) + (l * 64 + w * 8) * 64); } }

  // prologue: tile0 fully -> buf0; tile1 B-halves -> buf1
  STGH(A, rowA0, 0, &lA[0][0])
  STGH(A, rowA0 + 128, 0, &lA[0][8192])
  STGH(Bsrc, rowB0, 0, &lB[0][0])
  STGH(Bsrc, rowB0 + 128, 0, &lB[0][8192])
  STGH(Bsrc, rowB0, 64, &lB[1][0])
  STGH(Bsrc, rowB0 + 128, 64, &lB[1][8192])
  asm volatile("s_waitcnt vmcnt(4)" ::: "memory");
  __builtin_amdgcn_sched_barrier(0);
  __builtin_amdgcn_s_barrier();
  __builtin_amdgcn_sched_barrier(0);

  int xr = row16 & 7;
  for (int t = 0; t < 32; t++) {
    int cur = t & 1, nxt = cur ^ 1;
    const unsigned short* As = &lA[cur][wm * 8192];
    const unsigned short* Bs = &lB[cur][(wn >> 1) * 8192 + (wn & 1) * 64 * 64];
    s16x8 af[2][4], bf[2][4];

    // ---- p0: read af(mh0) 8 + bf(nh0) 4 ; stage A0(t+1) ; MFMA Q(0,0)
#pragma unroll
    for (int kk = 0; kk < 2; kk++) {
      int so = ((kk * 4 + grp) ^ xr) * 8;
#pragma unroll
      for (int i = 0; i < 4; i++)
        af[kk][i] = *(const s16x8*)(As + (i * 16 + row16) * 64 + so);
#pragma unroll
      for (int j = 0; j < 2; j++)
        bf[kk][j] = *(const s16x8*)(Bs + (j * 16 + row16) * 64 + so);
    }
    if (t + 1 < 32) STGH(A, rowA0, (t + 1) * 64, &lA[nxt][0])
    __builtin_amdgcn_s_barrier();
    asm volatile("s_waitcnt lgkmcnt(0)" ::: "memory");
    __builtin_amdgcn_sched_barrier(0);
    __builtin_amdgcn_s_setprio(1);
#pragma unroll
    for (int kk = 0; kk < 2; kk++)
#pragma unroll
      for (int i = 0; i < 4; i++)
#pragma unroll
        for (int j = 0; j < 2; j++)
          acc[i][j] = __builtin_amdgcn_mfma_f32_16x16x32_bf16(af[kk][i], bf[kk][j], acc[i][j], 0, 0, 0);
    __builtin_amdgcn_s_setprio(0);
    __builtin_amdgcn_s_barrier();

    // ---- p1: read bf(nh1) 4 ; stage A1(t+1) ; MFMA Q(0,1)
#pragma unroll
    for (int kk = 0; kk < 2; kk++) {
      int so = ((kk * 4 + grp) ^ xr) * 8;
#pragma unroll
      for (int j = 0; j < 2; j++)
        bf[kk][2 + j] = *(const s16x8*)(Bs + ((2 + j) * 16 + row16) * 64 + so);
    }
    if (t + 1 < 32) STGH(A, rowA0 + 128, (t + 1) * 64, &lA[nxt][8192])
    __builtin_amdgcn_s_barrier();
    asm volatile("s_waitcnt lgkmcnt(0)" ::: "memory");
    __builtin_amdgcn_sched_barrier(0);
    __builtin_amdgcn_s_setprio(1);
#pragma unroll
    for (int kk = 0; kk < 2; kk++)
#pragma unroll
      for (int i = 0; i < 4; i++)
#pragma unroll
        for (int j = 0; j < 2; j++)
          acc[i][2 + j] = __builtin_amdgcn_mfma_f32_16x16x32_bf16(af[kk][i], bf[kk][2 + j], acc[i][2 + j], 0, 0, 0);
    __builtin_amdgcn_s_setprio(0);
    __builtin_amdgcn_s_barrier();

    // ---- p2: read af(mh1) 8 ; stage B0(t+2) ; MFMA Q(1,1)
#pragma unroll
    for (int kk = 0; kk < 2; kk++) {
      int so = ((kk * 4 + grp) ^ xr) * 8;
#pragma unroll
      for (int i = 0; i < 4; i++)
        af[kk][i] = *(const s16x8*)(As + ((4 + i) * 16 + row16) * 64 + so);
    }
    if (t + 2 < 32) STGH(Bsrc, rowB0, (t + 2) * 64, &lB[cur][0])
    __builtin_amdgcn_s_barrier();
    asm volatile("s_waitcnt lgkmcnt(0)" ::: "memory");
    __builtin_amdgcn_sched_barrier(0);
    __builtin_amdgcn_s_setprio(1);
#pragma unroll
    for (int kk = 0; kk < 2; kk++)
#pragma unroll
      for (int i = 0; i < 4; i++)
#pragma unroll
        for (int j = 0; j < 2; j++)
          acc[4 + i][2 + j] = __builtin_amdgcn_mfma_f32_16x16x32_bf16(af[kk][i], bf[kk][2 + j], acc[4 + i][2 + j], 0, 0, 0);
    __builtin_amdgcn_s_setprio(0);
    __builtin_amdgcn_s_barrier();

    // ---- p3: no reads ; stage B1(t+2) ; MFMA Q(1,0) ; vmcnt ; barrier
    if (t + 2 < 32) STGH(Bsrc, rowB0 + 128, (t + 2) * 64, &lB[cur][8192])
    __builtin_amdgcn_s_setprio(1);
#pragma unroll
    for (int kk = 0; kk < 2; kk++)
#pragma unroll
      for (int i = 0; i < 4; i++)
#pragma unroll
        for (int j = 0; j < 2; j++)
          acc[4 + i][j] = __builtin_amdgcn_mfma_f32_16x16x32_bf16(af[kk][i], bf[kk][j], acc[4 + i][j], 0, 0, 0);
    __builtin_amdgcn_s_setprio(0);
    if (t < 30) asm volatile("s_waitcnt vmcnt(4)" ::: "memory");
    else if (t == 30) asm volatile("s_waitcnt vmcnt(0)" ::: "memory");
    __builtin_amdgcn_sched_barrier(0);
    __builtin_amdgcn_s_barrier();
    __builtin_amdgcn_sched_barrier(0);
  }
#undef STGH

  // epilogue; Q gets qscale*log2(e) folded so attn can use exp2
  const float QSC = 0.18033688011112042f;
  int row0 = rowA0 + wm * 128 + grp * 4;
  int cl0 = (tn - seg * 8) * 256 + wn * 64 + row16;
  if (seg == 0) {
#pragma unroll
    for (int i = 0; i < 8; i++)
#pragma unroll
      for (int j = 0; j < 4; j++) {
        int cl = cl0 + j * 16;
        float bvv = bq[cl];
#pragma unroll
        for (int r = 0; r < 4; r++)
          Qo[(size_t)(row0 + i * 16 + r) * 2048 + cl] = f2bf((acc[i][j][r] + bvv) * QSC);
      }
  } else if (seg == 1) {
#pragma unroll
    for (int i = 0; i < 8; i++)
#pragma unroll
      for (int j = 0; j < 4; j++) {
        int cl = cl0 + j * 16;
        float bvv = bk[cl];
#pragma unroll
        for (int r = 0; r < 4; r++)
          Ko[(size_t)(row0 + i * 16 + r) * 2048 + cl] = f2bf(acc[i][j][r] + bvv);
      }
  } else {
#pragma unroll
    for (int i = 0; i < 8; i++)
#pragma unroll
      for (int j = 0; j < 4; j++) {
        int cl = cl0 + j * 16;
        float bvv = bv[cl];
        int hh = cl >> 6, dd = cl & 63;
        int rowb = row0 + i * 16;
        int bb = rowb >> 10, s0v = rowb & 1023;
        u16x4 pk;
#pragma unroll
        for (int r = 0; r < 4; r++) pk[r] = f2bf(acc[i][j][r] + bvv);
        *(u16x4*)(Vo + (((size_t)(bb * H_ + hh)) * D_ + dd) * S_ + s0v) = pk;
      }
  }
}

// ---------------- O-proj GEMM (r6 gemm128 structure, 2 blk/CU) ------------
__global__ __launch_bounds__(256) void gemm_o(const unsigned short* __restrict__ A,
                                              const unsigned short* __restrict__ Bt,
                                              const float* __restrict__ bias,
                                              float* __restrict__ Cout) {
  __shared__ __align__(16) unsigned short lA[2][128 * 64];
  __shared__ __align__(16) unsigned short lB[2][128 * 64];
  int tid = threadIdx.x;
  int w = tid >> 6, lane = tid & 63;
  int row16 = lane & 15, grp = lane >> 4;
  int wm = w >> 1, wn = w & 1;
  int srow = tid >> 3;
  int sswz = ((tid & 7) ^ (srow & 7)) * 8;

  int nwg = gridDim.x;
  int bid = blockIdx.x;
  int swz = (bid & 7) * (nwg >> 3) + (bid >> 3);
  int tm = swz / 16, tn = swz % 16;
  int rowA0 = tm * 128;
  int rowB0 = tn * 128;

  f32x4 acc[4][4] = {};

#define STG4(G, L, R0, K0)                                                  \
  { _Pragma("unroll") for (int c = 0; c < 4; c++) {                         \
      gl_lds16((G) + (size_t)((R0) + c * 32 + srow) * 2048 + (K0) + sswz,   \
               (L) + (c * 32 + w * 8) * 64); } }

  STG4(A, &lA[0][0], rowA0, 0)
  STG4(Bt, &lB[0][0], rowB0, 0)
  STG4(A, &lA[1][0], rowA0, 64)
  STG4(Bt, &lB[1][0], rowB0, 64)

  int xr = row16 & 7;
  for (int t = 0; t < 32; t++) {
    if (t < 31) asm volatile("s_waitcnt vmcnt(8)" ::: "memory");
    else        asm volatile("s_waitcnt vmcnt(0)" ::: "memory");
    __builtin_amdgcn_sched_barrier(0);
    __builtin_amdgcn_s_barrier();
    __builtin_amdgcn_sched_barrier(0);
    const unsigned short* As = &lA[t & 1][0];
    const unsigned short* Bs = &lB[t & 1][0];
    s16x8 af[2][4], bf[2][4];
#pragma unroll
    for (int kk = 0; kk < 2; kk++) {
      int so = ((kk * 4 + grp) ^ xr) * 8;
#pragma unroll
      for (int i = 0; i < 4; i++)
        af[kk][i] = *(const s16x8*)(As + (wm * 64 + i * 16 + row16) * 64 + so);
#pragma unroll
      for (int j = 0; j < 4; j++)
        bf[kk][j] = *(const s16x8*)(Bs + (wn * 64 + j * 16 + row16) * 64 + so);
    }
    asm volatile("s_waitcnt lgkmcnt(0)" ::: "memory");
    __builtin_amdgcn_sched_barrier(0);
    __builtin_amdgcn_s_barrier();
    __builtin_amdgcn_sched_barrier(0);
    if (t < 30) {
      int k0n = (t + 2) * 64;
      STG4(A, &lA[t & 1][0], rowA0, k0n)
      STG4(Bt, &lB[t & 1][0], rowB0, k0n)
    }
    __builtin_amdgcn_s_setprio(1);
#pragma unroll
    for (int kk = 0; kk < 2; kk++)
#pragma unroll
      for (int i = 0; i < 4; i++)
#pragma unroll
        for (int j = 0; j < 4; j++)
          acc[i][j] = __builtin_amdgcn_mfma_f32_16x16x32_bf16(af[kk][i], bf[kk][j], acc[i][j], 0, 0, 0);
    __builtin_amdgcn_s_setprio(0);
  }
#undef STG4

  int row0 = rowA0 + wm * 64 + grp * 4;
  int col0 = rowB0 + wn * 64 + row16;
#pragma unroll
  for (int i = 0; i < 4; i++)
#pragma unroll
    for (int j = 0; j < 4; j++) {
      int col = col0 + j * 16;
      float bvv = bias[col];
#pragma unroll
      for (int r = 0; r < 4; r++)
        Cout[(size_t)(row0 + i * 16 + r) * 2048 + col] = acc[i][j][r] + bvv;
    }
}

// ---------------- flash attention (paired-causal, balanced) ----------------
__global__ __launch_bounds__(256, 4) void attnk(const unsigned short* __restrict__ Q,
                                                const unsigned short* __restrict__ K,
                                                const unsigned short* __restrict__ Vt,
                                                unsigned short* __restrict__ ctx) {
  __shared__ unsigned short KT[2][64 * 64];
  __shared__ unsigned short VT[2][64 * 64];
  __shared__ unsigned short Pl[4][16 * 64];
  int tid = threadIdx.x;
  int w = tid >> 6, lane = tid & 63;
  int row16 = lane & 15, grp = lane >> 4;
  int bid = blockIdx.x;
  int bh = bid >> 3;
  int p = bid & 7;
  int b = bh >> 5, h = bh & 31;
  int qgA = p, qgB = 15 - p;
  int qA = qgA * 64 + w * 16 + row16;
  int qB = qgB * 64 + w * 16 + row16;
  int nkc = qgB + 1;

  const unsigned short* qpA = Q + ((size_t)(b * S_ + qA)) * E_ + h * D_ + grp * 8;
  const unsigned short* qpB = Q + ((size_t)(b * S_ + qB)) * E_ + h * D_ + grp * 8;
  s16x8 qfA0 = *(const s16x8*)(qpA);
  s16x8 qfA1 = *(const s16x8*)(qpA + 32);
  s16x8 qfB0 = *(const s16x8*)(qpB);
  s16x8 qfB1 = *(const s16x8*)(qpB + 32);

  f32x4 oaccA[4] = {}, oaccB[4] = {};
  float mA = -1e30f, lAr = 0.f, mB = -1e30f, lBr = 0.f;

  int trow = tid >> 3;
  int tslot = tid & 7;
  const unsigned short* Kg = K + ((size_t)(b * S_)) * E_ + h * D_;
  const unsigned short* Vg = Vt + (((size_t)(b * H_ + h)) * D_) * S_;
  unsigned short* P = Pl[w];

  auto tstep = [&](s16x8 q0f, s16x8 q1f, int qloc, f32x4* oa, float& mr,
                   float& lr, bool diag, const unsigned short* Kt,
                   const unsigned short* Vl) {
    f32x4 s[4];
#pragma unroll
    for (int j = 0; j < 4; j++) {
      int krow = 16 * j + row16;
      s16x8 kf0 = *(const s16x8*)(Kt + krow * 64 + ((grp ^ (krow & 7)) * 8));
      s16x8 kf1 = *(const s16x8*)(Kt + krow * 64 + (((grp + 4) ^ (krow & 7)) * 8));
      f32x4 a = {};
      a = __builtin_amdgcn_mfma_f32_16x16x32_bf16(kf0, q0f, a, 0, 0, 0);
      a = __builtin_amdgcn_mfma_f32_16x16x32_bf16(kf1, q1f, a, 0, 0, 0);
      s[j] = a;
    }
    float mx = -1e30f;
    if (diag) {
#pragma unroll
      for (int j = 0; j < 4; j++)
#pragma unroll
        for (int r = 0; r < 4; r++) {
          int key = 16 * j + grp * 4 + r;
          float sv = (key <= qloc) ? s[j][r] : -1e30f;
          s[j][r] = sv;
          mx = fmaxf(mx, sv);
        }
    } else {
#pragma unroll
      for (int j = 0; j < 4; j++)
#pragma unroll
        for (int r = 0; r < 4; r++) mx = fmaxf(mx, s[j][r]);
    }
    mx = fmaxf(mx, __shfl_xor(mx, 16));
    mx = fmaxf(mx, __shfl_xor(mx, 32));
    float mn = fmaxf(mr, mx);
    float sc = exp2f(mr - mn);
    mr = mn;
    float rs = 0.f;
#pragma unroll
    for (int j = 0; j < 4; j++)
#pragma unroll
      for (int r = 0; r < 4; r++) {
        float e = exp2f(s[j][r] - mn);
        s[j][r] = e;
        rs += e;
      }
    rs += __shfl_xor(rs, 16);
    rs += __shfl_xor(rs, 32);
    lr = lr * sc + rs;
#pragma unroll
    for (int dt = 0; dt < 4; dt++) oa[dt] *= sc;
#pragma unroll
    for (int j = 0; j < 4; j++) {
      u16x4 pk;
#pragma unroll
      for (int r = 0; r < 4; r++) pk[r] = f2bf(s[j][r]);
      int s8 = 4 * j + grp;
      *(u16x4*)(P + row16 * 64 + ((s8 * 4) ^ ((row16 & 7) << 3))) = pk;
    }
    s16x8 pb0 = *(const s16x8*)(P + row16 * 64 + ((grp * 8) ^ ((row16 & 7) << 3)));
    s16x8 pb1 = *(const s16x8*)(P + row16 * 64 + (((4 + grp) * 8) ^ ((row16 & 7) << 3)));
#pragma unroll
    for (int dt = 0; dt < 4; dt++) {
      int drow = dt * 16 + row16;
      s16x8 vf0 = *(const s16x8*)(Vl + drow * 64 + ((grp ^ (drow & 7)) * 8));
      s16x8 vf1 = *(const s16x8*)(Vl + drow * 64 + (((grp + 4) ^ (drow & 7)) * 8));
      oa[dt] = __builtin_amdgcn_mfma_f32_16x16x32_bf16(vf0, pb0, oa[dt], 0, 0, 0);
      oa[dt] = __builtin_amdgcn_mfma_f32_16x16x32_bf16(vf1, pb1, oa[dt], 0, 0, 0);
    }
  };

#pragma unroll
  for (int c = 0; c < 2; c++) {
    int krow = c * 32 + trow;
    gl_lds16(Kg + (size_t)krow * E_ + ((tslot ^ (krow & 7)) * 8),
             &KT[0][0] + c * 2048 + w * 512);
    gl_lds16(Vg + (size_t)krow * S_ + ((tslot ^ (krow & 7)) * 8),
             &VT[0][0] + c * 2048 + w * 512);
  }
  __syncthreads();

  for (int kc = 0; kc < nkc; kc++) {
    int cur = kc & 1;
    if (kc + 1 < nkc) {
      int k0n = (kc + 1) * 64;
      int nxt = cur ^ 1;
#pragma unroll
      for (int c = 0; c < 2; c++) {
        int krow = c * 32 + trow;
        gl_lds16(Kg + (size_t)(k0n + krow) * E_ + ((tslot ^ (krow & 7)) * 8),
                 &KT[nxt][0] + c * 2048 + w * 512);
        gl_lds16(Vg + (size_t)krow * S_ + k0n + ((tslot ^ (krow & 7)) * 8),
                 &VT[nxt][0] + c * 2048 + w * 512);
      }
    }
    int k0 = kc * 64;
    const unsigned short* Kt = &KT[cur][0];
    const unsigned short* Vl = &VT[cur][0];

    tstep(qfB0, qfB1, qB - k0, oaccB, mB, lBr, kc == qgB, Kt, Vl);
    if (kc <= qgA)
      tstep(qfA0, qfA1, qA - k0, oaccA, mA, lAr, kc == qgA, Kt, Vl);
    __syncthreads();
  }

  float invB = 1.0f / lBr, invA = 1.0f / lAr;
  unsigned short* cpB = ctx + ((size_t)(b * S_ + qB)) * E_ + h * D_;
  unsigned short* cpA = ctx + ((size_t)(b * S_ + qA)) * E_ + h * D_;
#pragma unroll
  for (int dt = 0; dt < 4; dt++) {
    u16x4 oB, oA;
#pragma unroll
    for (int r = 0; r < 4; r++) {
      oB[r] = f2bf(oaccB[dt][r] * invB);
      oA[r] = f2bf(oaccA[dt][r] * invA);
    }
    *(u16x4*)(cpB + dt * 16 + grp * 4) = oB;
    *(u16x4*)(cpA + dt * 16 + grp * 4) = oA;
  }
}

extern "C" void kernel_launch(void* const* d_in, const int* in_sizes, int n_in,
                              void* d_out, int out_size, void* d_ws, size_t ws_size,
                              hipStream_t stream) {
  const float* X    = (const float*)d_in[0];
  const float* Wq   = (const float*)d_in[2];
  const float* bq   = (const float*)d_in[3];
  const float* Wk   = (const float*)d_in[4];
  const float* bk   = (const float*)d_in[5];
  const float* Wv   = (const float*)d_in[6];
  const float* bv   = (const float*)d_in[7];
  const float* Wo   = (const float*)d_in[8];
  const float* bo   = (const float*)d_in[9];
  float* out = (float*)d_out;

  // ws:    [0,16)MB Xbf (ctx after attn); [16,24) Wq; [24,32) Wk; [32,40) Wv;
  //        [40,56) Vt; [56,64) Wo
  // d_out: [0,16)MB Qbf; [16,32) Kbf (dead before gemm_o writes out)
  char* ws = (char*)d_ws;
  unsigned short* Xbf  = (unsigned short*)ws;
  unsigned short* Wqbf = (unsigned short*)(ws + (16u << 20));
  unsigned short* Wkbf = Wqbf + (size_t)E_ * E_;
  unsigned short* Wvbf = Wkbf + (size_t)E_ * E_;
  unsigned short* Vt   = (unsigned short*)(ws + (40u << 20));
  unsigned short* Wobf = (unsigned short*)(ws + (56u << 20));
  unsigned short* Qbf  = (unsigned short*)d_out;
  unsigned short* Kbf  = Qbf + (size_t)(B_ * S_) * E_;

  const int M = B_ * S_;   // 4096
  const int nX8 = (B_ * S_ * E_) / 8;
  const int nW8 = (E_ * E_) / 8;

  convertk<<<nX8 / 256, 256, 0, stream>>>(X, Xbf, nX8);
  convertw3<<<dim3(nW8 / 256, 3), 256, 0, stream>>>(Wq, Wk, Wv, Wqbf, nW8);
  convertk<<<nW8 / 256, 256, 0, stream>>>(Wo, Wobf, nW8);

  gemm_qkv8<<<(M / 256) * 24, 512, 0, stream>>>(
      Xbf, Wqbf, Wkbf, Wvbf, bq, bk, bv, Qbf, Kbf, Vt);

  attnk<<<B_ * H_ * 8, 256, 0, stream>>>(Qbf, Kbf, Vt, Xbf);

  gemm_o<<<(M / 128) * 16, 256, 0, stream>>>(Xbf, Wobf, bo, out);
}